// Round 3
// baseline (55.879 us; speedup 1.0000x reference)
//
#include <hip/hip_runtime.h>
#include <math.h>

constexpr int   NN  = 262144;     // nodes
constexpr int   NE  = 1048576;    // edges
constexpr int   NE2 = NE / 2;
constexpr float DTc = 0.1f;
constexpr float W1 = 1.0f, W2 = 0.5f, W3 = 2.0f, W4 = 0.5f;
constexpr float EPSc = 1e-6f;

typedef float __attribute__((ext_vector_type(2))) f32x2;
typedef float __attribute__((ext_vector_type(4))) f32x4;
typedef int   __attribute__((ext_vector_type(2))) i32x2;

struct V3 { float x, y, z; };
struct Q4 { float x, y, z, w; };

__device__ __forceinline__ V3 v3(float x, float y, float z) { V3 r{x, y, z}; return r; }
__device__ __forceinline__ V3 vadd(V3 a, V3 b) { return v3(a.x + b.x, a.y + b.y, a.z + b.z); }
__device__ __forceinline__ V3 vsub(V3 a, V3 b) { return v3(a.x - b.x, a.y - b.y, a.z - b.z); }
__device__ __forceinline__ V3 vscale(float s, V3 a) { return v3(s * a.x, s * a.y, s * a.z); }
__device__ __forceinline__ V3 vcross(V3 a, V3 b) {
    return v3(a.y * b.z - a.z * b.y, a.z * b.x - a.x * b.z, a.x * b.y - a.y * b.x);
}
__device__ __forceinline__ float vdot(V3 a, V3 b) { return a.x * b.x + a.y * b.y + a.z * b.z; }

__device__ __forceinline__ Q4 qmul(Q4 a, Q4 b) {
    Q4 r;
    r.w = a.w * b.w - (a.x * b.x + a.y * b.y + a.z * b.z);
    r.x = a.w * b.x + b.w * a.x + (a.y * b.z - a.z * b.y);
    r.y = a.w * b.y + b.w * a.y + (a.z * b.x - a.x * b.z);
    r.z = a.w * b.z + b.w * a.z + (a.x * b.y - a.y * b.x);
    return r;
}
__device__ __forceinline__ Q4 qconj(Q4 q) { Q4 r{-q.x, -q.y, -q.z, q.w}; return r; }
__device__ __forceinline__ V3 qrot(Q4 q, V3 x) {
    V3 v = v3(q.x, q.y, q.z);
    V3 c1 = vadd(vcross(v, x), vscale(q.w, x));
    return vadd(x, vscale(2.0f, vcross(v, c1)));
}
__device__ __forceinline__ V3 so3_log(Q4 q) {
    V3 v = v3(q.x, q.y, q.z);
    float n = sqrtf(vdot(v, v));
    float theta = 2.0f * atan2f(n, q.w);
    float factor;
    if (n < EPSc) {
        float w_safe = (fabsf(q.w) < EPSc) ? 1.0f : q.w;
        factor = 2.0f / w_safe;
    } else {
        factor = theta / n;
    }
    return vscale(factor, v);
}

__device__ __forceinline__ void edge_residual(V3 tm, Q4 qm, V3 t1, Q4 q1,
                                              V3 t2, Q4 q2, float* __restrict__ o) {
    // A = se3_inv(pose1)
    Q4 qa = qconj(q1);
    V3 ta = vscale(-1.0f, qrot(qa, t1));
    // B = A * pose2
    V3 tb = vadd(ta, qrot(qa, t2));
    Q4 qb = qmul(qa, q2);
    // C = se3_inv(vmot)
    Q4 qc = qconj(qm);
    V3 tc = vscale(-1.0f, qrot(qc, tm));
    // err = C * B
    V3 te = vadd(tc, qrot(qc, tb));
    Q4 qe = qmul(qc, qb);

    V3 phi = so3_log(qe);
    float th = sqrtf(vdot(phi, phi));
    float coef;
    if (th < EPSc) {
        coef = 1.0f / 12.0f + th * th / 720.0f;
    } else {
        float s, c;
        sincosf(th, &s, &c);
        coef = 1.0f / (th * th) - (1.0f + c) / (2.0f * th * s);
    }
    V3 pxt = vcross(phi, te);
    V3 tau = vadd(vsub(te, vscale(0.5f, pxt)), vscale(coef, vcross(phi, pxt)));

    f32x2* o2 = (f32x2*)o;  // 24B record stride -> 8B aligned
    f32x2 a = {W1 * tau.x, W1 * tau.y};
    f32x2 b = {W1 * tau.z, W1 * phi.x};
    f32x2 c = {W1 * phi.y, W1 * phi.z};
    __builtin_nontemporal_store(a, o2);
    __builtin_nontemporal_store(b, o2 + 1);
    __builtin_nontemporal_store(c, o2 + 2);
}

// Pre-pass: pad pose (7 floats) into 32B-aligned records in ws:
// rec[2i]   = (tx, ty, tz, --)
// rec[2i+1] = (qx, qy, qz, qw)
__global__ __launch_bounds__(256) void pad_pose_kernel(const float* __restrict__ pose,
                                                       f32x4* __restrict__ pp) {
    int i = blockIdx.x * blockDim.x + threadIdx.x;
    if (i >= NN) return;
    const float* p = pose + 7 * (size_t)i;
    f32x4 t = {p[0], p[1], p[2], 0.0f};
    f32x4 q = {p[3], p[4], p[5], p[6]};
    pp[2 * (size_t)i]     = t;
    pp[2 * (size_t)i + 1] = q;
}

__global__ __launch_bounds__(256) void vigraph_main(
    const float* __restrict__ pose, const float* __restrict__ vel,
    const float* __restrict__ vmot, const float* __restrict__ imu_drot,
    const float* __restrict__ body_dvel, const float* __restrict__ body_dpos,
    const int* __restrict__ vlink, const f32x4* __restrict__ pp,
    float* __restrict__ out)
{
    int tid = blockIdx.x * blockDim.x + threadIdx.x;
    if (tid < NE2) {
        int e0 = tid, e1 = tid + NE2;
        // ---- issue ALL loads for both edges up front (ILP over gather latency)
        i32x2 l0 = __builtin_nontemporal_load((const i32x2*)vlink + e0);
        i32x2 l1 = __builtin_nontemporal_load((const i32x2*)vlink + e1);
        const float* pm0 = vmot + 7 * (size_t)e0;
        const float* pm1 = vmot + 7 * (size_t)e1;
        float m0[7], m1[7];
#pragma unroll
        for (int k = 0; k < 7; ++k) m0[k] = __builtin_nontemporal_load(pm0 + k);
#pragma unroll
        for (int k = 0; k < 7; ++k) m1[k] = __builtin_nontemporal_load(pm1 + k);
        f32x4 t10 = pp[2 * (size_t)l0.x], q10 = pp[2 * (size_t)l0.x + 1];
        f32x4 t20 = pp[2 * (size_t)l0.y], q20 = pp[2 * (size_t)l0.y + 1];
        f32x4 t11 = pp[2 * (size_t)l1.x], q11 = pp[2 * (size_t)l1.x + 1];
        f32x4 t21 = pp[2 * (size_t)l1.y], q21 = pp[2 * (size_t)l1.y + 1];

        edge_residual(v3(m0[0], m0[1], m0[2]), Q4{m0[3], m0[4], m0[5], m0[6]},
                      v3(t10.x, t10.y, t10.z), Q4{q10.x, q10.y, q10.z, q10.w},
                      v3(t20.x, t20.y, t20.z), Q4{q20.x, q20.y, q20.z, q20.w},
                      out + 6 * (size_t)e0);
        edge_residual(v3(m1[0], m1[1], m1[2]), Q4{m1[3], m1[4], m1[5], m1[6]},
                      v3(t11.x, t11.y, t11.z), Q4{q11.x, q11.y, q11.z, q11.w},
                      v3(t21.x, t21.y, t21.z), Q4{q21.x, q21.y, q21.z, q21.w},
                      out + 6 * (size_t)e1);
    } else {
        int i = tid - NE2;
        if (i >= NN - 1) return;
        const float* pa = pose + 7 * (size_t)i;
        const float* pb = pose + 7 * (size_t)(i + 1);
        V3 tr1 = v3(pa[0], pa[1], pa[2]); Q4 r1 = {pa[3], pa[4], pa[5], pa[6]};
        V3 tr2 = v3(pb[0], pb[1], pb[2]); Q4 r2 = {pb[3], pb[4], pb[5], pb[6]};
        V3 v1 = v3(vel[3 * (size_t)i],       vel[3 * (size_t)i + 1],       vel[3 * (size_t)i + 2]);
        V3 v2 = v3(vel[3 * (size_t)(i + 1)], vel[3 * (size_t)(i + 1) + 1], vel[3 * (size_t)(i + 1) + 2]);
        V3 bdv = v3(__builtin_nontemporal_load(body_dvel + 3 * (size_t)i),
                    __builtin_nontemporal_load(body_dvel + 3 * (size_t)i + 1),
                    __builtin_nontemporal_load(body_dvel + 3 * (size_t)i + 2));
        V3 bdp = v3(__builtin_nontemporal_load(body_dpos + 3 * (size_t)i),
                    __builtin_nontemporal_load(body_dpos + 3 * (size_t)i + 1),
                    __builtin_nontemporal_load(body_dpos + 3 * (size_t)i + 2));
        Q4 idr = {__builtin_nontemporal_load(imu_drot + 4 * (size_t)i),
                  __builtin_nontemporal_load(imu_drot + 4 * (size_t)i + 1),
                  __builtin_nontemporal_load(imu_drot + 4 * (size_t)i + 2),
                  __builtin_nontemporal_load(imu_drot + 4 * (size_t)i + 3)};

        V3 imu_dvel = qrot(r1, bdv);
        V3 adjvel = vsub(imu_dvel, vsub(v2, v1));
        Q4 qrel = qmul(idr, qmul(qconj(r1), r2));
        V3 imurot = so3_log(qrel);
        V3 imu_dpos = vadd(qrot(r1, bdp), vscale(DTc, v1));
        V3 transvel = vsub(imu_dpos, vsub(tr2, tr1));

        size_t base = (size_t)6 * NE;
        size_t nm1 = (size_t)(NN - 1);
        float* oa = out + base + 3 * (size_t)i;
        oa[0] = W2 * adjvel.x; oa[1] = W2 * adjvel.y; oa[2] = W2 * adjvel.z;
        float* ob = out + base + 3 * nm1 + 3 * (size_t)i;
        ob[0] = W3 * imurot.x; ob[1] = W3 * imurot.y; ob[2] = W3 * imurot.z;
        float* oc = out + base + 6 * nm1 + 3 * (size_t)i;
        oc[0] = W4 * transvel.x; oc[1] = W4 * transvel.y; oc[2] = W4 * transvel.z;
    }
}

// Fallback (no workspace): 1 edge/thread, raw pose gathers.
__global__ __launch_bounds__(256) void vigraph_fallback(
    const float* __restrict__ pose, const float* __restrict__ vel,
    const float* __restrict__ vmot, const float* __restrict__ imu_drot,
    const float* __restrict__ body_dvel, const float* __restrict__ body_dpos,
    const int* __restrict__ vlink, float* __restrict__ out)
{
    int tid = blockIdx.x * blockDim.x + threadIdx.x;
    if (tid < NE) {
        int e = tid;
        const float* pm = vmot + 7 * (size_t)e;
        int i1 = vlink[2 * (size_t)e];
        int i2 = vlink[2 * (size_t)e + 1];
        const float* p1 = pose + 7 * (size_t)i1;
        const float* p2 = pose + 7 * (size_t)i2;
        edge_residual(v3(pm[0], pm[1], pm[2]), Q4{pm[3], pm[4], pm[5], pm[6]},
                      v3(p1[0], p1[1], p1[2]), Q4{p1[3], p1[4], p1[5], p1[6]},
                      v3(p2[0], p2[1], p2[2]), Q4{p2[3], p2[4], p2[5], p2[6]},
                      out + 6 * (size_t)e);
    } else {
        int i = tid - NE;
        if (i >= NN - 1) return;
        const float* pa = pose + 7 * (size_t)i;
        const float* pb = pose + 7 * (size_t)(i + 1);
        V3 tr1 = v3(pa[0], pa[1], pa[2]); Q4 r1 = {pa[3], pa[4], pa[5], pa[6]};
        V3 tr2 = v3(pb[0], pb[1], pb[2]); Q4 r2 = {pb[3], pb[4], pb[5], pb[6]};
        V3 v1 = v3(vel[3 * (size_t)i], vel[3 * (size_t)i + 1], vel[3 * (size_t)i + 2]);
        V3 v2 = v3(vel[3 * (size_t)(i + 1)], vel[3 * (size_t)(i + 1) + 1], vel[3 * (size_t)(i + 1) + 2]);
        V3 bdv = v3(body_dvel[3 * (size_t)i], body_dvel[3 * (size_t)i + 1], body_dvel[3 * (size_t)i + 2]);
        V3 bdp = v3(body_dpos[3 * (size_t)i], body_dpos[3 * (size_t)i + 1], body_dpos[3 * (size_t)i + 2]);
        Q4 idr = {imu_drot[4 * (size_t)i], imu_drot[4 * (size_t)i + 1],
                  imu_drot[4 * (size_t)i + 2], imu_drot[4 * (size_t)i + 3]};
        V3 imu_dvel = qrot(r1, bdv);
        V3 adjvel = vsub(imu_dvel, vsub(v2, v1));
        Q4 qrel = qmul(idr, qmul(qconj(r1), r2));
        V3 imurot = so3_log(qrel);
        V3 imu_dpos = vadd(qrot(r1, bdp), vscale(DTc, v1));
        V3 transvel = vsub(imu_dpos, vsub(tr2, tr1));
        size_t base = (size_t)6 * NE;
        size_t nm1 = (size_t)(NN - 1);
        float* oa = out + base + 3 * (size_t)i;
        oa[0] = W2 * adjvel.x; oa[1] = W2 * adjvel.y; oa[2] = W2 * adjvel.z;
        float* ob = out + base + 3 * nm1 + 3 * (size_t)i;
        ob[0] = W3 * imurot.x; ob[1] = W3 * imurot.y; ob[2] = W3 * imurot.z;
        float* oc = out + base + 6 * nm1 + 3 * (size_t)i;
        oc[0] = W4 * transvel.x; oc[1] = W4 * transvel.y; oc[2] = W4 * transvel.z;
    }
}

extern "C" void kernel_launch(void* const* d_in, const int* in_sizes, int n_in,
                              void* d_out, int out_size, void* d_ws, size_t ws_size,
                              hipStream_t stream) {
    const float* pose      = (const float*)d_in[0];
    const float* vel       = (const float*)d_in[1];
    const float* vmot      = (const float*)d_in[2];
    const float* imu_drot  = (const float*)d_in[3];
    const float* body_dvel = (const float*)d_in[4];
    const float* body_dpos = (const float*)d_in[5];
    const int*   vlink     = (const int*)d_in[6];
    float* out = (float*)d_out;

    const size_t padded_bytes = (size_t)NN * 32;
    if (ws_size >= padded_bytes) {
        f32x4* pp = (f32x4*)d_ws;
        pad_pose_kernel<<<NN / 256, 256, 0, stream>>>(pose, pp);
        int total = NE2 + (NN - 1);
        int grid = (total + 255) / 256;
        vigraph_main<<<grid, 256, 0, stream>>>(pose, vel, vmot, imu_drot,
                                               body_dvel, body_dpos, vlink, pp, out);
    } else {
        int total = NE + (NN - 1);
        int grid = (total + 255) / 256;
        vigraph_fallback<<<grid, 256, 0, stream>>>(pose, vel, vmot, imu_drot,
                                                   body_dvel, body_dpos, vlink, out);
    }
}

// Round 4
// 38.464 us; speedup vs baseline: 1.4527x; 1.4527x over previous
//
#include <hip/hip_runtime.h>
#include <math.h>

constexpr int   NN  = 262144;     // nodes
constexpr int   NE  = 1048576;    // edges
constexpr float DTc = 0.1f;
constexpr float W1 = 1.0f, W2 = 0.5f, W3 = 2.0f, W4 = 0.5f;
constexpr float EPSc = 1e-6f;

typedef float    __attribute__((ext_vector_type(2))) f32x2;
typedef float    __attribute__((ext_vector_type(4))) f32x4;
typedef float    __attribute__((ext_vector_type(4), aligned(4))) f32x4u;  // 4B-aligned vec load
typedef float    __attribute__((ext_vector_type(2), aligned(4))) f32x2u;
typedef int      __attribute__((ext_vector_type(2))) i32x2;
typedef _Float16 __attribute__((ext_vector_type(8))) f16x8;               // 16B pose record

struct V3 { float x, y, z; };
struct Q4 { float x, y, z, w; };

__device__ __forceinline__ V3 v3(float x, float y, float z) { V3 r{x, y, z}; return r; }
__device__ __forceinline__ V3 vadd(V3 a, V3 b) { return v3(a.x + b.x, a.y + b.y, a.z + b.z); }
__device__ __forceinline__ V3 vsub(V3 a, V3 b) { return v3(a.x - b.x, a.y - b.y, a.z - b.z); }
__device__ __forceinline__ V3 vscale(float s, V3 a) { return v3(s * a.x, s * a.y, s * a.z); }
__device__ __forceinline__ V3 vcross(V3 a, V3 b) {
    return v3(a.y * b.z - a.z * b.y, a.z * b.x - a.x * b.z, a.x * b.y - a.y * b.x);
}
__device__ __forceinline__ float vdot(V3 a, V3 b) { return a.x * b.x + a.y * b.y + a.z * b.z; }

__device__ __forceinline__ Q4 qmul(Q4 a, Q4 b) {
    Q4 r;
    r.w = a.w * b.w - (a.x * b.x + a.y * b.y + a.z * b.z);
    r.x = a.w * b.x + b.w * a.x + (a.y * b.z - a.z * b.y);
    r.y = a.w * b.y + b.w * a.y + (a.z * b.x - a.x * b.z);
    r.z = a.w * b.z + b.w * a.z + (a.x * b.y - a.y * b.x);
    return r;
}
__device__ __forceinline__ Q4 qconj(Q4 q) { Q4 r{-q.x, -q.y, -q.z, q.w}; return r; }
__device__ __forceinline__ V3 qrot(Q4 q, V3 x) {
    V3 v = v3(q.x, q.y, q.z);
    V3 c1 = vadd(vcross(v, x), vscale(q.w, x));
    return vadd(x, vscale(2.0f, vcross(v, c1)));
}
__device__ __forceinline__ V3 so3_log(Q4 q) {
    V3 v = v3(q.x, q.y, q.z);
    float n = sqrtf(vdot(v, v));
    float theta = 2.0f * atan2f(n, q.w);
    float factor;
    if (n < EPSc) {
        float w_safe = (fabsf(q.w) < EPSc) ? 1.0f : q.w;
        factor = 2.0f / w_safe;
    } else {
        factor = theta / n;
    }
    return vscale(factor, v);
}

__device__ __forceinline__ void edge_residual(V3 tm, Q4 qm, V3 t1, Q4 q1,
                                              V3 t2, Q4 q2, float* __restrict__ o) {
    Q4 qa = qconj(q1);
    V3 ta = vscale(-1.0f, qrot(qa, t1));
    V3 tb = vadd(ta, qrot(qa, t2));
    Q4 qb = qmul(qa, q2);
    Q4 qc = qconj(qm);
    V3 tc = vscale(-1.0f, qrot(qc, tm));
    V3 te = vadd(tc, qrot(qc, tb));
    Q4 qe = qmul(qc, qb);

    V3 phi = so3_log(qe);
    float th = sqrtf(vdot(phi, phi));
    float coef;
    if (th < EPSc) {
        coef = 1.0f / 12.0f + th * th / 720.0f;
    } else {
        float s, c;
        sincosf(th, &s, &c);
        coef = 1.0f / (th * th) - (1.0f + c) / (2.0f * th * s);
    }
    V3 pxt = vcross(phi, te);
    V3 tau = vadd(vsub(te, vscale(0.5f, pxt)), vscale(coef, vcross(phi, pxt)));

    f32x2* o2 = (f32x2*)o;  // 24B stride -> 8B aligned
    f32x2 a = {W1 * tau.x, W1 * tau.y};
    f32x2 b = {W1 * tau.z, W1 * phi.x};
    f32x2 c = {W1 * phi.y, W1 * phi.z};
    __builtin_nontemporal_store(a, o2);
    __builtin_nontemporal_store(b, o2 + 1);
    __builtin_nontemporal_store(c, o2 + 2);
}

// Kernel 1: node residuals + build fp16 pose table (16B records, 4MB total).
// Record: [tx ty tz qx qy qz qw 0] as 8 halves.
__global__ __launch_bounds__(256) void node_pack_kernel(
    const float* __restrict__ pose, const float* __restrict__ vel,
    const float* __restrict__ imu_drot, const float* __restrict__ body_dvel,
    const float* __restrict__ body_dpos, f16x8* __restrict__ ppH,
    float* __restrict__ out)
{
    int i = blockIdx.x * blockDim.x + threadIdx.x;
    if (i >= NN) return;
    // pose i: two overlapping 16B loads over the 28B record (4B-aligned OK)
    f32x4u pa0 = *(const f32x4u*)(pose + 7 * (size_t)i);      // tx ty tz qx
    f32x4u pa1 = *(const f32x4u*)(pose + 7 * (size_t)i + 3);  // qx qy qz qw
    f16x8 rec = {(_Float16)pa0.x, (_Float16)pa0.y, (_Float16)pa0.z,
                 (_Float16)pa1.x, (_Float16)pa1.y, (_Float16)pa1.z,
                 (_Float16)pa1.w, (_Float16)0.0f};
    ppH[i] = rec;
    if (i >= NN - 1) return;

    V3 tr1 = v3(pa0.x, pa0.y, pa0.z); Q4 r1 = {pa1.x, pa1.y, pa1.z, pa1.w};
    f32x4u pb0 = *(const f32x4u*)(pose + 7 * (size_t)(i + 1));
    f32x4u pb1 = *(const f32x4u*)(pose + 7 * (size_t)(i + 1) + 3);
    V3 tr2 = v3(pb0.x, pb0.y, pb0.z); Q4 r2 = {pb1.x, pb1.y, pb1.z, pb1.w};

    f32x4u vv = *(const f32x4u*)(vel + 3 * (size_t)i);        // v1x v1y v1z v2x
    f32x2u vw = *(const f32x2u*)(vel + 3 * (size_t)i + 4);    // v2y v2z
    V3 v1 = v3(vv.x, vv.y, vv.z);
    V3 v2 = v3(vv.w, vw.x, vw.y);
    V3 bdv = v3(body_dvel[3 * (size_t)i], body_dvel[3 * (size_t)i + 1], body_dvel[3 * (size_t)i + 2]);
    V3 bdp = v3(body_dpos[3 * (size_t)i], body_dpos[3 * (size_t)i + 1], body_dpos[3 * (size_t)i + 2]);
    f32x4 id4 = *(const f32x4*)(imu_drot + 4 * (size_t)i);    // 16B aligned
    Q4 idr = {id4.x, id4.y, id4.z, id4.w};

    V3 imu_dvel = qrot(r1, bdv);
    V3 adjvel = vsub(imu_dvel, vsub(v2, v1));
    Q4 qrel = qmul(idr, qmul(qconj(r1), r2));
    V3 imurot = so3_log(qrel);
    V3 imu_dpos = vadd(qrot(r1, bdp), vscale(DTc, v1));
    V3 transvel = vsub(imu_dpos, vsub(tr2, tr1));

    size_t base = (size_t)6 * NE;
    size_t nm1 = (size_t)(NN - 1);
    float* oa = out + base + 3 * (size_t)i;
    oa[0] = W2 * adjvel.x; oa[1] = W2 * adjvel.y; oa[2] = W2 * adjvel.z;
    float* ob = out + base + 3 * nm1 + 3 * (size_t)i;
    ob[0] = W3 * imurot.x; ob[1] = W3 * imurot.y; ob[2] = W3 * imurot.z;
    float* oc = out + base + 6 * nm1 + 3 * (size_t)i;
    oc[0] = W4 * transvel.x; oc[1] = W4 * transvel.y; oc[2] = W4 * transvel.z;
}

// Kernel 2: edge residuals. vmot LDS-staged coalesced; pose via one 16B fp16
// gather per endpoint (4MB table, L2-friendly); nt loads keep table resident.
__global__ __launch_bounds__(256) void edge_kernel(
    const float* __restrict__ vmot, const int* __restrict__ vlink,
    const f16x8* __restrict__ ppH, float* __restrict__ out)
{
    __shared__ float smv[256 * 7];
    int e0 = blockIdx.x * 256;
    // cooperative coalesced stage of 256 edges' vmot (7168B = 448 float4)
    const f32x4* src = (const f32x4*)(vmot + (size_t)e0 * 7);
    {
        int idx = threadIdx.x;
        ((f32x4*)smv)[idx] = __builtin_nontemporal_load(src + idx);
        idx += 256;
        if (idx < 448) ((f32x4*)smv)[idx] = __builtin_nontemporal_load(src + idx);
    }
    int e = e0 + threadIdx.x;
    i32x2 l = __builtin_nontemporal_load((const i32x2*)vlink + e);
    f16x8 g1 = ppH[l.x];   // one 16B gather per endpoint
    f16x8 g2 = ppH[l.y];
    __syncthreads();
    float m[7];
#pragma unroll
    for (int k = 0; k < 7; ++k) m[k] = smv[7 * threadIdx.x + k];

    V3 t1 = v3((float)g1[0], (float)g1[1], (float)g1[2]);
    Q4 q1 = {(float)g1[3], (float)g1[4], (float)g1[5], (float)g1[6]};
    V3 t2 = v3((float)g2[0], (float)g2[1], (float)g2[2]);
    Q4 q2 = {(float)g2[3], (float)g2[4], (float)g2[5], (float)g2[6]};

    edge_residual(v3(m[0], m[1], m[2]), Q4{m[3], m[4], m[5], m[6]},
                  t1, q1, t2, q2, out + 6 * (size_t)e);
}

// Fallback (no workspace): 1 edge/thread, raw f32 pose gathers.
__global__ __launch_bounds__(256) void vigraph_fallback(
    const float* __restrict__ pose, const float* __restrict__ vel,
    const float* __restrict__ vmot, const float* __restrict__ imu_drot,
    const float* __restrict__ body_dvel, const float* __restrict__ body_dpos,
    const int* __restrict__ vlink, float* __restrict__ out)
{
    int tid = blockIdx.x * blockDim.x + threadIdx.x;
    if (tid < NE) {
        int e = tid;
        const float* pm = vmot + 7 * (size_t)e;
        int i1 = vlink[2 * (size_t)e];
        int i2 = vlink[2 * (size_t)e + 1];
        const float* p1 = pose + 7 * (size_t)i1;
        const float* p2 = pose + 7 * (size_t)i2;
        edge_residual(v3(pm[0], pm[1], pm[2]), Q4{pm[3], pm[4], pm[5], pm[6]},
                      v3(p1[0], p1[1], p1[2]), Q4{p1[3], p1[4], p1[5], p1[6]},
                      v3(p2[0], p2[1], p2[2]), Q4{p2[3], p2[4], p2[5], p2[6]},
                      out + 6 * (size_t)e);
    } else {
        int i = tid - NE;
        if (i >= NN - 1) return;
        const float* pa = pose + 7 * (size_t)i;
        const float* pb = pose + 7 * (size_t)(i + 1);
        V3 tr1 = v3(pa[0], pa[1], pa[2]); Q4 r1 = {pa[3], pa[4], pa[5], pa[6]};
        V3 tr2 = v3(pb[0], pb[1], pb[2]); Q4 r2 = {pb[3], pb[4], pb[5], pb[6]};
        V3 v1 = v3(vel[3 * (size_t)i], vel[3 * (size_t)i + 1], vel[3 * (size_t)i + 2]);
        V3 v2 = v3(vel[3 * (size_t)(i + 1)], vel[3 * (size_t)(i + 1) + 1], vel[3 * (size_t)(i + 1) + 2]);
        V3 bdv = v3(body_dvel[3 * (size_t)i], body_dvel[3 * (size_t)i + 1], body_dvel[3 * (size_t)i + 2]);
        V3 bdp = v3(body_dpos[3 * (size_t)i], body_dpos[3 * (size_t)i + 1], body_dpos[3 * (size_t)i + 2]);
        Q4 idr = {imu_drot[4 * (size_t)i], imu_drot[4 * (size_t)i + 1],
                  imu_drot[4 * (size_t)i + 2], imu_drot[4 * (size_t)i + 3]};
        V3 imu_dvel = qrot(r1, bdv);
        V3 adjvel = vsub(imu_dvel, vsub(v2, v1));
        Q4 qrel = qmul(idr, qmul(qconj(r1), r2));
        V3 imurot = so3_log(qrel);
        V3 imu_dpos = vadd(qrot(r1, bdp), vscale(DTc, v1));
        V3 transvel = vsub(imu_dpos, vsub(tr2, tr1));
        size_t base = (size_t)6 * NE;
        size_t nm1 = (size_t)(NN - 1);
        float* oa = out + base + 3 * (size_t)i;
        oa[0] = W2 * adjvel.x; oa[1] = W2 * adjvel.y; oa[2] = W2 * adjvel.z;
        float* ob = out + base + 3 * nm1 + 3 * (size_t)i;
        ob[0] = W3 * imurot.x; ob[1] = W3 * imurot.y; ob[2] = W3 * imurot.z;
        float* oc = out + base + 6 * nm1 + 3 * (size_t)i;
        oc[0] = W4 * transvel.x; oc[1] = W4 * transvel.y; oc[2] = W4 * transvel.z;
    }
}

extern "C" void kernel_launch(void* const* d_in, const int* in_sizes, int n_in,
                              void* d_out, int out_size, void* d_ws, size_t ws_size,
                              hipStream_t stream) {
    const float* pose      = (const float*)d_in[0];
    const float* vel       = (const float*)d_in[1];
    const float* vmot      = (const float*)d_in[2];
    const float* imu_drot  = (const float*)d_in[3];
    const float* body_dvel = (const float*)d_in[4];
    const float* body_dpos = (const float*)d_in[5];
    const int*   vlink     = (const int*)d_in[6];
    float* out = (float*)d_out;

    const size_t table_bytes = (size_t)NN * 16;
    if (ws_size >= table_bytes) {
        f16x8* ppH = (f16x8*)d_ws;
        node_pack_kernel<<<NN / 256, 256, 0, stream>>>(pose, vel, imu_drot,
                                                       body_dvel, body_dpos, ppH, out);
        edge_kernel<<<NE / 256, 256, 0, stream>>>(vmot, vlink, ppH, out);
    } else {
        int total = NE + (NN - 1);
        int grid = (total + 255) / 256;
        vigraph_fallback<<<grid, 256, 0, stream>>>(pose, vel, vmot, imu_drot,
                                                   body_dvel, body_dpos, vlink, out);
    }
}